// Round 2
// baseline (28177.051 us; speedup 1.0000x reference)
//
#include <hip/hip_runtime.h>
#include <math.h>

// ---------------- problem constants ----------------
constexpr int BB = 2, TT = 20;
constexpr int IMG = 224, PATCH = 16, CH = 3;
constexpr int DIM = 768, DEPTH = 12, HEADS = 12, DH = 64, MLP = 3072;
constexpr int NPATCH = 196;            // (224/16)^2
constexpr int NTOK = 199;              // 196 + cls + 2 face
constexpr int BT = BB * TT;            // 40
constexpr int MROWS = BT * NTOK;       // 7960
constexpr int INNER = HEADS * DH;      // 768
constexpr int QKVDIM = 3 * INNER;      // 2304

// ---------------- helpers ----------------
__device__ __forceinline__ float gelu_f(float x) {
    return 0.5f * x * (1.0f + erff(x * 0.70710678118654752f));
}

// ---------------- im2col: img (40,3,224,224) -> A (7840, 768) ----------------
__global__ void im2col_k(const float* __restrict__ img, float* __restrict__ A) {
    int idx = blockIdx.x * 256 + threadIdx.x;           // 7840*768 total
    int k = idx % 768;                                  // NOTE: 768 not pow2 — must use %
    int m = idx / 768;
    int bt = m / NPATCH, p = m % NPATCH;
    int c = k >> 8;                 // /256 (256 IS pow2)
    int r = k & 255;
    int ph = r >> 4, pw = r & 15;
    int py = p / 14, px = p % 14;
    A[idx] = img[(((size_t)bt * CH + c) * IMG + (py * 16 + ph)) * IMG + (px * 16 + pw)];
}

// ---------------- generic fp32 tiled GEMM ----------------
// C[m][n] = sum_k A[m][k] * B[k][n]        (BTL=false, B is K x N row-major)
//         = sum_k A[m][k] * B[n][k]        (BTL=true,  B is N x K row-major)
// EPI: 0 -> C = acc
//      1 -> C = C + acc + bias             (residual in-place)
//      2 -> C = gelu(acc + bias)
// Tile 128x128, BK=16, 256 threads, 8x8 per thread. N % 128 == 0 required.
template <int EPI, bool BTL>
__global__ __launch_bounds__(256) void gemm_k(
        const float* __restrict__ A, const float* __restrict__ B,
        const float* __restrict__ bias, float* __restrict__ C,
        int Mm, int N, int K) {
    __shared__ float As[16][132];
    __shared__ float Bs[16][132];

    const int tid = threadIdx.x;
    const int m0 = blockIdx.y * 128;
    const int n0 = blockIdx.x * 128;
    const int ty = tid >> 4;          // 0..15
    const int tx = tid & 15;          // 0..15

    float acc[8][8];
#pragma unroll
    for (int i = 0; i < 8; ++i)
#pragma unroll
        for (int j = 0; j < 8; ++j) acc[i][j] = 0.f;

    const int a_m = tid >> 2;           // 0..63
    const int a_k4 = (tid & 3) * 4;     // 0,4,8,12
    const int b_k = tid >> 5;           // 0..7
    const int b_n4 = (tid & 31) * 4;    // 0..124

    for (int k0 = 0; k0 < K; k0 += 16) {
        // ---- load A tile (transposed into As[k][m]) ----
#pragma unroll
        for (int pass = 0; pass < 2; ++pass) {
            int m = m0 + a_m + pass * 64;
            float4 v = make_float4(0.f, 0.f, 0.f, 0.f);
            if (m < Mm)
                v = *reinterpret_cast<const float4*>(A + (size_t)m * K + k0 + a_k4);
            int ml = a_m + pass * 64;
            As[a_k4 + 0][ml] = v.x;
            As[a_k4 + 1][ml] = v.y;
            As[a_k4 + 2][ml] = v.z;
            As[a_k4 + 3][ml] = v.w;
        }
        // ---- load B tile ----
        if (!BTL) {
#pragma unroll
            for (int pass = 0; pass < 2; ++pass) {
                int k = b_k + pass * 8;
                float4 v = *reinterpret_cast<const float4*>(
                    B + (size_t)(k0 + k) * N + n0 + b_n4);
                *reinterpret_cast<float4*>(&Bs[k][b_n4]) = v;
            }
        } else {
#pragma unroll
            for (int pass = 0; pass < 2; ++pass) {
                int n = n0 + a_m + pass * 64;   // N % 128 == 0, no guard
                float4 v = *reinterpret_cast<const float4*>(
                    B + (size_t)n * K + k0 + a_k4);
                int nl = a_m + pass * 64;
                Bs[a_k4 + 0][nl] = v.x;
                Bs[a_k4 + 1][nl] = v.y;
                Bs[a_k4 + 2][nl] = v.z;
                Bs[a_k4 + 3][nl] = v.w;
            }
        }
        __syncthreads();

#pragma unroll
        for (int k = 0; k < 16; ++k) {
            float4 a0 = *reinterpret_cast<const float4*>(&As[k][ty * 8]);
            float4 a1 = *reinterpret_cast<const float4*>(&As[k][ty * 8 + 4]);
            float4 b0 = *reinterpret_cast<const float4*>(&Bs[k][tx * 8]);
            float4 b1 = *reinterpret_cast<const float4*>(&Bs[k][tx * 8 + 4]);
            float av[8] = {a0.x, a0.y, a0.z, a0.w, a1.x, a1.y, a1.z, a1.w};
            float bv[8] = {b0.x, b0.y, b0.z, b0.w, b1.x, b1.y, b1.z, b1.w};
#pragma unroll
            for (int i = 0; i < 8; ++i)
#pragma unroll
                for (int j = 0; j < 8; ++j) acc[i][j] += av[i] * bv[j];
        }
        __syncthreads();
    }

    // ---- epilogue ----
#pragma unroll
    for (int i = 0; i < 8; ++i) {
        int m = m0 + ty * 8 + i;
        if (m < Mm) {
            float* crow = C + (size_t)m * N + n0 + tx * 8;
#pragma unroll
            for (int jj = 0; jj < 2; ++jj) {
                float4 o;
                if (EPI == 0) {
                    o.x = acc[i][jj * 4 + 0];
                    o.y = acc[i][jj * 4 + 1];
                    o.z = acc[i][jj * 4 + 2];
                    o.w = acc[i][jj * 4 + 3];
                } else if (EPI == 1) {
                    float4 bz = *reinterpret_cast<const float4*>(bias + n0 + tx * 8 + jj * 4);
                    float4 r = *reinterpret_cast<const float4*>(crow + jj * 4);
                    o.x = acc[i][jj * 4 + 0] + bz.x + r.x;
                    o.y = acc[i][jj * 4 + 1] + bz.y + r.y;
                    o.z = acc[i][jj * 4 + 2] + bz.z + r.z;
                    o.w = acc[i][jj * 4 + 3] + bz.w + r.w;
                } else {
                    float4 bz = *reinterpret_cast<const float4*>(bias + n0 + tx * 8 + jj * 4);
                    o.x = gelu_f(acc[i][jj * 4 + 0] + bz.x);
                    o.y = gelu_f(acc[i][jj * 4 + 1] + bz.y);
                    o.z = gelu_f(acc[i][jj * 4 + 2] + bz.z);
                    o.w = gelu_f(acc[i][jj * 4 + 3] + bz.w);
                }
                *reinterpret_cast<float4*>(crow + jj * 4) = o;
            }
        }
    }
}

// ---------------- token assembly ----------------
__global__ void assemble_k(const float* __restrict__ Xc, const float* __restrict__ face,
                           const float* __restrict__ conv_b, const float* __restrict__ pos,
                           const float* __restrict__ time_emb, const float* __restrict__ cls,
                           float* __restrict__ X) {
    int idx = blockIdx.x * 256 + threadIdx.x;   // 40*199*768
    int d = idx % DIM;
    int tok = (idx / DIM) % NTOK;
    int bt = idx / (DIM * NTOK);
    int t = bt % TT;
    float v;
    if (tok == 0) {
        v = cls[d] + pos[d];
    } else if (tok <= NPATCH) {
        v = Xc[((size_t)bt * NPATCH + (tok - 1)) * DIM + d] + conv_b[d] + pos[tok * DIM + d];
    } else {
        v = face[((size_t)bt * 2 + (tok - NPATCH - 1)) * DIM + d];
    }
    v += time_emb[t * DIM + d];
    X[idx] = v;
}

// ---------------- LayerNorm: one wave per row, two-pass (stable) ----------------
__global__ __launch_bounds__(64) void ln_k(const float* __restrict__ X,
                                           const float* __restrict__ s,
                                           const float* __restrict__ b,
                                           float* __restrict__ out) {
    int row = blockIdx.x;
    int lane = threadIdx.x;
    const float4* xr = reinterpret_cast<const float4*>(X + (size_t)row * DIM);
    float4 v0 = xr[lane], v1 = xr[lane + 64], v2 = xr[lane + 128];
    float sum = v0.x + v0.y + v0.z + v0.w + v1.x + v1.y + v1.z + v1.w +
                v2.x + v2.y + v2.z + v2.w;
#pragma unroll
    for (int off = 32; off; off >>= 1) sum += __shfl_xor(sum, off);
    float mean = sum * (1.f / DIM);
    // second pass: sum of squared deviations (matches reference's two-pass form)
    float sq = 0.f;
#pragma unroll
    for (int c = 0; c < 3; ++c) {
        float4 v = (c == 0) ? v0 : (c == 1) ? v1 : v2;
        float dx = v.x - mean, dy = v.y - mean, dz = v.z - mean, dw = v.w - mean;
        sq += dx * dx + dy * dy + dz * dz + dw * dw;
    }
#pragma unroll
    for (int off = 32; off; off >>= 1) sq += __shfl_xor(sq, off);
    float var = sq * (1.f / DIM);
    float rstd = rsqrtf(var + 1e-5f);
    const float4* sr = reinterpret_cast<const float4*>(s);
    const float4* br = reinterpret_cast<const float4*>(b);
    float4* orow = reinterpret_cast<float4*>(out + (size_t)row * DIM);
#pragma unroll
    for (int c = 0; c < 3; ++c) {
        float4 v = (c == 0) ? v0 : (c == 1) ? v1 : v2;
        float4 sc = sr[lane + 64 * c];
        float4 bc = br[lane + 64 * c];
        float4 o;
        o.x = (v.x - mean) * rstd * sc.x + bc.x;
        o.y = (v.y - mean) * rstd * sc.y + bc.y;
        o.z = (v.z - mean) * rstd * sc.z + bc.z;
        o.w = (v.w - mean) * rstd * sc.w + bc.w;
        orow[lane + 64 * c] = o;
    }
}

// ---------------- fused attention: one wave per (bt, head, query row) ----------------
__global__ __launch_bounds__(64) void attn_k(const float* __restrict__ qkv,
                                             float* __restrict__ O) {
    int i = blockIdx.x;      // query token
    int h = blockIdx.y;
    int bt = blockIdx.z;
    int lane = threadIdx.x;

    __shared__ __align__(16) float qsh[DH];
    __shared__ float psh[NTOK + 1];

    const float* base = qkv + (size_t)bt * NTOK * QKVDIM;
    qsh[lane] = base[(size_t)i * QKVDIM + h * DH + lane];
    __syncthreads();

    const float4* q4 = reinterpret_cast<const float4*>(qsh);
    float vals[4];
    float mx = -1e30f;
#pragma unroll
    for (int r = 0; r < 4; ++r) {
        int j = lane + 64 * r;
        vals[r] = -1e30f;
        if (j < NTOK) {
            const float4* kr = reinterpret_cast<const float4*>(
                base + (size_t)j * QKVDIM + INNER + h * DH);
            float d = 0.f;
#pragma unroll
            for (int kk = 0; kk < 16; ++kk) {
                float4 kv = kr[kk];
                float4 qv = q4[kk];
                d += qv.x * kv.x + qv.y * kv.y + qv.z * kv.z + qv.w * kv.w;
            }
            vals[r] = d * 0.125f;   // DH^-0.5
        }
        mx = fmaxf(mx, vals[r]);
    }
#pragma unroll
    for (int off = 32; off; off >>= 1) mx = fmaxf(mx, __shfl_xor(mx, off));

    float ssum = 0.f;
#pragma unroll
    for (int r = 0; r < 4; ++r) {
        int j = lane + 64 * r;
        if (j < NTOK) {
            float e = expf(vals[r] - mx);
            ssum += e;
            psh[j] = e;
        }
    }
#pragma unroll
    for (int off = 32; off; off >>= 1) ssum += __shfl_xor(ssum, off);
    float inv = 1.f / ssum;
    __syncthreads();

    // PV: lane = output dim d
    float o = 0.f;
    const float* vbase = base + 2 * INNER + h * DH + lane;
    for (int j = 0; j < NTOK; ++j) {
        o += psh[j] * vbase[(size_t)j * QKVDIM];
    }
    O[((size_t)bt * NTOK + i) * DIM + h * DH + lane] = o * inv;
}

// ---------------- output gather ----------------
__global__ void out_k(const float* __restrict__ X, float* __restrict__ out) {
    int idx = blockIdx.x * 256 + threadIdx.x;    // 40*199*768 total
    const int R = BT * DIM;                      // 30720
    float v;
    if (idx < R) {                               // x[:,0,:]
        int bt = idx / DIM, d = idx % DIM;
        v = X[((size_t)bt * NTOK + 0) * DIM + d];
    } else if (idx < 2 * R) {                    // x[:,197,:]
        int r = idx - R;
        int bt = r / DIM, d = r % DIM;
        v = X[((size_t)bt * NTOK + 197) * DIM + d];
    } else if (idx < 3 * R) {                    // x[:,198,:]
        int r = idx - 2 * R;
        int bt = r / DIM, d = r % DIM;
        v = X[((size_t)bt * NTOK + 198) * DIM + d];
    } else {                                     // x[:,1:197,:]
        int r = idx - 3 * R;
        int bt = r / (NPATCH * DIM);
        int rem = r % (NPATCH * DIM);
        int tok = rem / DIM + 1;
        int d = rem % DIM;
        v = X[((size_t)bt * NTOK + tok) * DIM + d];
    }
    out[idx] = v;
}

// ---------------- host orchestration ----------------
extern "C" void kernel_launch(void* const* d_in, const int* in_sizes, int n_in,
                              void* d_out, int out_size, void* d_ws, size_t ws_size,
                              hipStream_t stream) {
    const float* img      = (const float*)d_in[0];
    const float* face     = (const float*)d_in[1];
    const float* conv_w   = (const float*)d_in[2];
    const float* conv_b   = (const float*)d_in[3];
    const float* pos_emb  = (const float*)d_in[4];
    const float* time_emb = (const float*)d_in[5];
    const float* cls_tok  = (const float*)d_in[6];
    const float* ln1_s    = (const float*)d_in[7];
    const float* ln1_b    = (const float*)d_in[8];
    const float* qkv_w    = (const float*)d_in[9];
    const float* out_w    = (const float*)d_in[10];
    const float* out_b    = (const float*)d_in[11];
    const float* ln2_s    = (const float*)d_in[12];
    const float* ln2_b    = (const float*)d_in[13];
    const float* ff_w1    = (const float*)d_in[14];
    const float* ff_b1    = (const float*)d_in[15];
    const float* ff_w2    = (const float*)d_in[16];
    const float* ff_w2b   = (const float*)d_in[17];
    float* outp = (float*)d_out;

    // workspace layout (floats)
    const size_t XSZ = (size_t)BT * NTOK * DIM;          // 6,113,280
    float* X   = (float*)d_ws;
    float* H   = X + XSZ;
    float* O   = H + XSZ;
    float* TMP = O + XSZ;
    float* Aim = TMP;                                    // 7840*768
    float* Xc  = TMP + (size_t)BT * NPATCH * DIM;        // 7840*768
    float* QKV = TMP;                                    // 7960*2304
    float* F   = TMP;                                    // 7960*3072
    // total ws use: 3*XSZ + 7960*3072 = 171.2 MB

    const int PM = BT * NPATCH;                          // 7840

    // 1) im2col + conv GEMM (B transposed layout) + assembly
    im2col_k<<<(PM * DIM) / 256, 256, 0, stream>>>(img, Aim);
    {
        dim3 g(DIM / 128, (PM + 127) / 128);
        gemm_k<0, true><<<g, 256, 0, stream>>>(Aim, conv_w, nullptr, Xc, PM, DIM, DIM);
    }
    assemble_k<<<(BT * NTOK * DIM) / 256, 256, 0, stream>>>(
        Xc, face, conv_b, pos_emb, time_emb, cls_tok, X);

    // 2) transformer layers
    for (int l = 0; l < DEPTH; ++l) {
        ln_k<<<MROWS, 64, 0, stream>>>(X, ln1_s + l * DIM, ln1_b + l * DIM, H);
        {
            dim3 g(QKVDIM / 128, (MROWS + 127) / 128);
            gemm_k<0, false><<<g, 256, 0, stream>>>(
                H, qkv_w + (size_t)l * DIM * QKVDIM, nullptr, QKV, MROWS, QKVDIM, DIM);
        }
        {
            dim3 g(NTOK, HEADS, BT);
            attn_k<<<g, 64, 0, stream>>>(QKV, O);
        }
        {
            dim3 g(DIM / 128, (MROWS + 127) / 128);
            gemm_k<1, false><<<g, 256, 0, stream>>>(
                O, out_w + (size_t)l * INNER * DIM, out_b + l * DIM, X, MROWS, DIM, INNER);
        }
        ln_k<<<MROWS, 64, 0, stream>>>(X, ln2_s + l * DIM, ln2_b + l * DIM, H);
        {
            dim3 g(MLP / 128, (MROWS + 127) / 128);
            gemm_k<2, false><<<g, 256, 0, stream>>>(
                H, ff_w1 + (size_t)l * DIM * MLP, ff_b1 + l * MLP, F, MROWS, MLP, DIM);
        }
        {
            dim3 g(DIM / 128, (MROWS + 127) / 128);
            gemm_k<1, false><<<g, 256, 0, stream>>>(
                F, ff_w2 + (size_t)l * MLP * DIM, ff_w2b + l * DIM, X, MROWS, DIM, MLP);
        }
    }

    // 3) outputs
    out_k<<<(BT * NTOK * DIM) / 256, 256, 0, stream>>>(X, outp);
}

// Round 5
// 23677.753 us; speedup vs baseline: 1.1900x; 1.1900x over previous
//
#include <hip/hip_runtime.h>
#include <hip/hip_bf16.h>
#include <math.h>

// ---------------- problem constants ----------------
constexpr int BB = 2, TT = 20;
constexpr int IMG = 224, PATCH = 16, CH = 3;
constexpr int DIM = 768, DEPTH = 12, HEADS = 12, DH = 64, MLP = 3072;
constexpr int NPATCH = 196;
constexpr int NTOK = 199;
constexpr int BT = BB * TT;            // 40
constexpr int MROWS = BT * NTOK;       // 7960
constexpr int INNER = HEADS * DH;      // 768
constexpr int QKVDIM = 3 * INNER;      // 2304

typedef short bf16x8 __attribute__((ext_vector_type(8)));
typedef float f32x4 __attribute__((ext_vector_type(4)));

__device__ __forceinline__ ushort f2bf(float x) {
    __hip_bfloat16 h = __float2bfloat16(x);
    return *reinterpret_cast<ushort*>(&h);
}
__device__ __forceinline__ float gelu_f(float x) {
    return 0.5f * x * (1.0f + erff(x * 0.70710678118654752f));
}

// ---------------- weight transpose+cast: W[K][N] f32 -> Wt[N][K] bf16 ----------------
__global__ void tr_k(const float* __restrict__ W, ushort* __restrict__ Wt, int K, int N) {
    __shared__ float t[32][33];
    int n0 = blockIdx.x * 32, k0 = blockIdx.y * 32;
    int tx = threadIdx.x, ty = threadIdx.y;
#pragma unroll
    for (int p = 0; p < 4; ++p)
        t[ty + 8 * p][tx] = W[(size_t)(k0 + ty + 8 * p) * N + n0 + tx];
    __syncthreads();
#pragma unroll
    for (int p = 0; p < 4; ++p)
        Wt[(size_t)(n0 + ty + 8 * p) * K + k0 + tx] = f2bf(t[tx][ty + 8 * p]);
}

// ---------------- cast f32 -> bf16 ----------------
__global__ void cast_k(const float* __restrict__ in, ushort* __restrict__ out, int n) {
    int i = blockIdx.x * 256 + threadIdx.x;
    if (i < n) out[i] = f2bf(in[i]);
}

// ---------------- im2col: img (40,3,224,224) -> A (7840, 768) bf16 ----------------
__global__ void im2col_k(const float* __restrict__ img, ushort* __restrict__ A) {
    int idx = blockIdx.x * 256 + threadIdx.x;
    int k = idx % 768;                 // 768 not pow2 -> must use %
    int m = idx / 768;
    int bt = m / NPATCH, p = m % NPATCH;
    int c = k >> 8;
    int r = k & 255;
    int ph = r >> 4, pw = r & 15;
    int py = p / 14, px = p % 14;
    A[idx] = f2bf(img[(((size_t)bt * CH + c) * IMG + (py * 16 + ph)) * IMG + (px * 16 + pw)]);
}

// ---------------- bf16 MFMA GEMM ----------------
// C[m][n] = sum_k A[m][k] * Bt[n][k];  A,Bt bf16 row-major.  N%128==0, K%32==0.
// EPI 0: C f32 = acc;  EPI 1: C f32 += acc + bias;  EPI 2: C bf16 = gelu(acc+bias)
// LDS: per 128-row tile, BK=32, row stride 40 ushorts (80 B), k stored LINEARLY.
// A/B operand layout for mfma_f32_16x16x32_bf16: lane (g=l>>4, r=l&15) holds
// elements k = 8g+e (e=0..7, contiguous) of row r  -> one aligned ds_read_b128
// at ushort offset row*40 + g*8.  (Same contiguous-chunk pattern as CDNA3 fp8
// 16x16x32; consistent with HK's row-major-LDS + ds_read_b128 feeding.)
// C/D layout (m89-verified): col = l&15, row = (l>>4)*4 + reg.
template <int EPI>
__global__ __launch_bounds__(256) void mgemm_k(
        const ushort* __restrict__ A, const ushort* __restrict__ Bt,
        const float* __restrict__ bias, void* __restrict__ Cv,
        int Mm, int N, int K) {
    __shared__ __align__(16) ushort As[128 * 40];
    __shared__ __align__(16) ushort Bs[128 * 40];
    const int tid = threadIdx.x;
    const int l = tid & 63, w = tid >> 6;
    const int wr = w >> 1, wc = w & 1;
    const int g = l >> 4, r = l & 15;
    const int m0 = blockIdx.y * 128, n0 = blockIdx.x * 128;

    f32x4 acc[4][4];
#pragma unroll
    for (int i = 0; i < 4; ++i)
#pragma unroll
        for (int j = 0; j < 4; ++j) acc[i][j] = (f32x4){0.f, 0.f, 0.f, 0.f};

    // staging: thread t -> row=t>>1, chunks c = 2*(t&1)+p (p=0,1); chunk c = 8 bf16 at k=8c
    const int srow = tid >> 1;
    const int c0 = (tid & 1) * 2;
    const bool aval = (m0 + srow) < Mm;
    const ushort* aptr = A + (size_t)(m0 + srow) * K;
    const ushort* bptr = Bt + (size_t)(n0 + srow) * K;

    for (int kt = 0; kt < K; kt += 32) {
        int4 ra[2], rb[2];
#pragma unroll
        for (int p = 0; p < 2; ++p) {
            int c = c0 + p;
            ra[p] = aval ? *reinterpret_cast<const int4*>(aptr + kt + 8 * c)
                         : make_int4(0, 0, 0, 0);
            rb[p] = *reinterpret_cast<const int4*>(bptr + kt + 8 * c);
        }
        __syncthreads();
#pragma unroll
        for (int p = 0; p < 2; ++p) {
            int c = c0 + p;
            int base = srow * 40 + 8 * c;      // linear k within the row
            *reinterpret_cast<int4*>(&As[base]) = ra[p];
            *reinterpret_cast<int4*>(&Bs[base]) = rb[p];
        }
        __syncthreads();

        bf16x8 af[4], bfr[4];
#pragma unroll
        for (int fi = 0; fi < 4; ++fi)
            af[fi] = *reinterpret_cast<const bf16x8*>(&As[(wr * 64 + fi * 16 + r) * 40 + g * 8]);
#pragma unroll
        for (int fj = 0; fj < 4; ++fj)
            bfr[fj] = *reinterpret_cast<const bf16x8*>(&Bs[(wc * 64 + fj * 16 + r) * 40 + g * 8]);
#pragma unroll
        for (int fi = 0; fi < 4; ++fi)
#pragma unroll
            for (int fj = 0; fj < 4; ++fj)
                acc[fi][fj] = __builtin_amdgcn_mfma_f32_16x16x32_bf16(
                    af[fi], bfr[fj], acc[fi][fj], 0, 0, 0);
    }

    // epilogue: D lane mapping (m89): col = r, row = g*4 + e within each 16x16 fragment
    float* Cf = (float*)Cv;
    ushort* Cu = (ushort*)Cv;
#pragma unroll
    for (int fi = 0; fi < 4; ++fi) {
#pragma unroll
        for (int e = 0; e < 4; ++e) {
            int row = m0 + wr * 64 + fi * 16 + g * 4 + e;
            if (row < Mm) {
#pragma unroll
                for (int fj = 0; fj < 4; ++fj) {
                    int col = n0 + wc * 64 + fj * 16 + r;
                    float v = acc[fi][fj][e];
                    if (EPI == 0) {
                        Cf[(size_t)row * N + col] = v;
                    } else if (EPI == 1) {
                        Cf[(size_t)row * N + col] += v + bias[col];
                    } else {
                        Cu[(size_t)row * N + col] = f2bf(gelu_f(v + bias[col]));
                    }
                }
            }
        }
    }
}

// ---------------- token assembly (fp32 X) ----------------
__global__ void assemble_k(const float* __restrict__ Xc, const float* __restrict__ face,
                           const float* __restrict__ conv_b, const float* __restrict__ pos,
                           const float* __restrict__ time_emb, const float* __restrict__ cls,
                           float* __restrict__ X) {
    int idx = blockIdx.x * 256 + threadIdx.x;
    int d = idx % DIM;
    int tok = (idx / DIM) % NTOK;
    int bt = idx / (DIM * NTOK);
    int t = bt % TT;
    float v;
    if (tok == 0) {
        v = cls[d] + pos[d];
    } else if (tok <= NPATCH) {
        v = Xc[((size_t)bt * NPATCH + (tok - 1)) * DIM + d] + conv_b[d] + pos[tok * DIM + d];
    } else {
        v = face[((size_t)bt * 2 + (tok - NPATCH - 1)) * DIM + d];
    }
    v += time_emb[t * DIM + d];
    X[idx] = v;
}

// ---------------- LayerNorm: one wave per row, two-pass, bf16 out ----------------
__global__ __launch_bounds__(64) void ln_k(const float* __restrict__ X,
                                           const float* __restrict__ s,
                                           const float* __restrict__ b,
                                           ushort* __restrict__ out) {
    int row = blockIdx.x;
    int lane = threadIdx.x;
    const float4* xr = reinterpret_cast<const float4*>(X + (size_t)row * DIM);
    float4 v0 = xr[lane], v1 = xr[lane + 64], v2 = xr[lane + 128];
    float sum = v0.x + v0.y + v0.z + v0.w + v1.x + v1.y + v1.z + v1.w +
                v2.x + v2.y + v2.z + v2.w;
#pragma unroll
    for (int off = 32; off; off >>= 1) sum += __shfl_xor(sum, off);
    float mean = sum * (1.f / DIM);
    float sq = 0.f;
#pragma unroll
    for (int c = 0; c < 3; ++c) {
        float4 v = (c == 0) ? v0 : (c == 1) ? v1 : v2;
        float dx = v.x - mean, dy = v.y - mean, dz = v.z - mean, dw = v.w - mean;
        sq += dx * dx + dy * dy + dz * dz + dw * dw;
    }
#pragma unroll
    for (int off = 32; off; off >>= 1) sq += __shfl_xor(sq, off);
    float rstd = rsqrtf(sq * (1.f / DIM) + 1e-5f);
    const float4* sr = reinterpret_cast<const float4*>(s);
    const float4* br = reinterpret_cast<const float4*>(b);
    ushort4* orow = reinterpret_cast<ushort4*>(out + (size_t)row * DIM);
#pragma unroll
    for (int c = 0; c < 3; ++c) {
        float4 v = (c == 0) ? v0 : (c == 1) ? v1 : v2;
        float4 sc = sr[lane + 64 * c];
        float4 bc = br[lane + 64 * c];
        ushort4 o;
        o.x = f2bf((v.x - mean) * rstd * sc.x + bc.x);
        o.y = f2bf((v.y - mean) * rstd * sc.y + bc.y);
        o.z = f2bf((v.z - mean) * rstd * sc.z + bc.z);
        o.w = f2bf((v.w - mean) * rstd * sc.w + bc.w);
        orow[lane + 64 * c] = o;
    }
}

// ---------------- fused attention: one block per (bt, head) ----------------
// Static LDS (139,520 B < 160 KiB; 1 block/CU): K rows, V transposed, per-wave Q/P.
__global__ __launch_bounds__(256) void attn_k(const float* __restrict__ qkv,
                                              ushort* __restrict__ O) {
    __shared__ __align__(16) float Kl[256][68];     // 69,632 B (rows 199..255 garbage, masked)
    __shared__ __align__(16) float Vt[64][204];     // 52,224 B
    __shared__ __align__(16) float Qs[4][4][68];    //  4,352 B (wave-private slots)
    __shared__ __align__(16) float Ps[4][4][208];   // 13,312 B (wave-private slots)

    const int h = blockIdx.x % HEADS;
    const int bt = blockIdx.x / HEADS;
    const int tid = threadIdx.x, l = tid & 63, w = tid >> 6;
    const float* base = qkv + (size_t)bt * NTOK * QKVDIM;

    // stage K rows and V transposed
    for (int it = 0; it < 50; ++it) {
        int idx = tid + it * 256;
        int j = idx >> 6, d = idx & 63;
        if (j < NTOK) {
            Kl[j][d] = base[(size_t)j * QKVDIM + INNER + h * DH + d];
            Vt[d][j] = base[(size_t)j * QKVDIM + 2 * INNER + h * DH + d];
        }
    }
    if (tid < 64) {
        Vt[tid][199] = 0.f; Vt[tid][200] = 0.f; Vt[tid][201] = 0.f;
        Vt[tid][202] = 0.f; Vt[tid][203] = 0.f;
    }
    __syncthreads();

    const int qp = l >> 4;     // query slot (Q staging)
    const int qq = l & 15;     // quad (Q staging)

    for (int G = w; G < 50; G += 4) {           // groups of 4 queries; per-wave, no barrier
        const int ibase = G * 4;
        {   // stage this group's Q into the wave-private slot (same-wave DS ops are in-order)
            int i = min(ibase + qp, NTOK - 1);
            float4 qv = *reinterpret_cast<const float4*>(
                base + (size_t)i * QKVDIM + h * DH + qq * 4);
            *reinterpret_cast<float4*>(&Qs[w][qp][qq * 4]) = qv;
        }
        float acc[4][4];
#pragma unroll
        for (int p = 0; p < 4; ++p)
#pragma unroll
            for (int kc = 0; kc < 4; ++kc) acc[p][kc] = 0.f;

#pragma unroll
        for (int kk = 0; kk < 16; ++kk) {
            float4 q4[4];
#pragma unroll
            for (int p = 0; p < 4; ++p)
                q4[p] = *reinterpret_cast<const float4*>(&Qs[w][p][kk * 4]);
#pragma unroll
            for (int kc = 0; kc < 4; ++kc) {
                int j = l + 64 * kc;            // rows >=199 are garbage, masked below
                float4 k4 = *reinterpret_cast<const float4*>(&Kl[j][kk * 4]);
#pragma unroll
                for (int p = 0; p < 4; ++p)
                    acc[p][kc] += q4[p].x * k4.x + q4[p].y * k4.y +
                                  q4[p].z * k4.z + q4[p].w * k4.w;
            }
        }
        // softmax per query (masked lanes fully overwritten -> NaN-safe)
        float pexp[4][4];
#pragma unroll
        for (int p = 0; p < 4; ++p) {
            float mx = -1e30f;
#pragma unroll
            for (int kc = 0; kc < 4; ++kc) {
                int j = l + 64 * kc;
                float sc = (j < NTOK) ? acc[p][kc] * 0.125f : -1e30f;
                acc[p][kc] = sc;
                mx = fmaxf(mx, sc);
            }
#pragma unroll
            for (int off = 32; off; off >>= 1) mx = fmaxf(mx, __shfl_xor(mx, off));
            float ss = 0.f;
#pragma unroll
            for (int kc = 0; kc < 4; ++kc) {
                float e = __expf(acc[p][kc] - mx);
                pexp[p][kc] = e;
                ss += e;
            }
#pragma unroll
            for (int off = 32; off; off >>= 1) ss += __shfl_xor(ss, off);
            float inv = 1.f / ss;
#pragma unroll
            for (int kc = 0; kc < 4; ++kc) {
                int j = l + 64 * kc;
                if (j < 200) Ps[w][p][j] = pexp[p][kc] * inv;   // [199] = 0 (masked)
            }
        }
        // PV: lane = output dim d
        float o[4] = {0.f, 0.f, 0.f, 0.f};
#pragma unroll
        for (int jq = 0; jq < 50; ++jq) {
            float4 v4 = *reinterpret_cast<const float4*>(&Vt[l][jq * 4]);
#pragma unroll
            for (int p = 0; p < 4; ++p) {
                float4 p4 = *reinterpret_cast<const float4*>(&Ps[w][p][jq * 4]);
                o[p] += p4.x * v4.x + p4.y * v4.y + p4.z * v4.z + p4.w * v4.w;
            }
        }
#pragma unroll
        for (int p = 0; p < 4; ++p) {
            int i = ibase + p;
            if (i < NTOK)
                O[((size_t)bt * NTOK + i) * DIM + h * DH + l] = f2bf(o[p]);
        }
    }
}

// ---------------- output gather ----------------
__global__ void out_k(const float* __restrict__ X, float* __restrict__ out) {
    int idx = blockIdx.x * 256 + threadIdx.x;
    const int R = BT * DIM;
    float v;
    if (idx < R) {
        int bt = idx / DIM, d = idx % DIM;
        v = X[((size_t)bt * NTOK + 0) * DIM + d];
    } else if (idx < 2 * R) {
        int r = idx - R;
        int bt = r / DIM, d = r % DIM;
        v = X[((size_t)bt * NTOK + 197) * DIM + d];
    } else if (idx < 3 * R) {
        int r = idx - 2 * R;
        int bt = r / DIM, d = r % DIM;
        v = X[((size_t)bt * NTOK + 198) * DIM + d];
    } else {
        int r = idx - 3 * R;
        int bt = r / (NPATCH * DIM);
        int rem = r % (NPATCH * DIM);
        int tok = rem / DIM + 1;
        int d = rem % DIM;
        v = X[((size_t)bt * NTOK + tok) * DIM + d];
    }
    out[idx] = v;
}

// ---------------- host orchestration ----------------
extern "C" void kernel_launch(void* const* d_in, const int* in_sizes, int n_in,
                              void* d_out, int out_size, void* d_ws, size_t ws_size,
                              hipStream_t stream) {
    const float* img      = (const float*)d_in[0];
    const float* face     = (const float*)d_in[1];
    const float* conv_w   = (const float*)d_in[2];
    const float* conv_b   = (const float*)d_in[3];
    const float* pos_emb  = (const float*)d_in[4];
    const float* time_emb = (const float*)d_in[5];
    const float* cls_tok  = (const float*)d_in[6];
    const float* ln1_s    = (const float*)d_in[7];
    const float* ln1_b    = (const float*)d_in[8];
    const float* qkv_w    = (const float*)d_in[9];
    const float* out_w    = (const float*)d_in[10];
    const float* out_b    = (const float*)d_in[11];
    const float* ln2_s    = (const float*)d_in[12];
    const float* ln2_b    = (const float*)d_in[13];
    const float* ff_w1    = (const float*)d_in[14];
    const float* ff_b1    = (const float*)d_in[15];
    const float* ff_w2    = (const float*)d_in[16];
    const float* ff_w2b   = (const float*)d_in[17];
    float* outp = (float*)d_out;

    // workspace layout (float units)
    const size_t XSZ = (size_t)MROWS * DIM;          // 6,113,280 f
    const size_t HSLOT = XSZ / 2;                    // bf16 buffer in f-slots
    float* X    = (float*)d_ws;
    ushort* H   = (ushort*)(X + XSZ);
    ushort* Ob  = (ushort*)(X + XSZ + HSLOT);
    float* TMP  = X + XSZ + 2 * HSLOT;               // QKV f32 / F bf16 / im2col+Xc
    float* QKV  = TMP;                               // 7960*2304 f
    ushort* F   = (ushort*)TMP;                      // 7960*3072 us (after QKV dead)
    ushort* Aim = (ushort*)TMP;                      // 7840*768 us = 3,010,560 f-slots
    float* Xc   = TMP + 3010560;                     // 7840*768 f, AFTER Aim (no overlap!)
    float* WEND = TMP + (size_t)MROWS * QKVDIM;      // weights after the QKV region
    ushort* WqT = (ushort*)WEND;                     // 2304*768
    ushort* WoT = WqT + 2304 * 768;                  // 768*768
    ushort* W1T = WoT + 768 * 768;                   // 3072*768
    ushort* W2T = W1T + 3072 * 768;                  // 768*3072
    ushort* CW  = W2T + 768 * 3072;                  // conv weights bf16 (768*768)
    // total: (XSZ + 2*HSLOT + MROWS*QKVDIM)*4 + 7,667,712*2 ≈ 137.6 MB

    const int PM = BT * NPATCH;                      // 7840

    // 1) conv patch embed (bf16 MFMA) + assembly
    cast_k<<<(768 * 768 + 255) / 256, 256, 0, stream>>>(conv_w, CW, 768 * 768);
    im2col_k<<<(PM * DIM) / 256, 256, 0, stream>>>(img, Aim);
    {
        dim3 g(DIM / 128, (PM + 127) / 128);
        mgemm_k<0><<<g, 256, 0, stream>>>(Aim, CW, nullptr, Xc, PM, DIM, DIM);
    }
    assemble_k<<<(BT * NTOK * DIM) / 256, 256, 0, stream>>>(
        Xc, face, conv_b, pos_emb, time_emb, cls_tok, X);

    // 2) transformer layers
    for (int l = 0; l < DEPTH; ++l) {
        tr_k<<<dim3(QKVDIM / 32, DIM / 32), dim3(32, 8), 0, stream>>>(
            qkv_w + (size_t)l * DIM * QKVDIM, WqT, DIM, QKVDIM);
        tr_k<<<dim3(DIM / 32, INNER / 32), dim3(32, 8), 0, stream>>>(
            out_w + (size_t)l * INNER * DIM, WoT, INNER, DIM);
        tr_k<<<dim3(MLP / 32, DIM / 32), dim3(32, 8), 0, stream>>>(
            ff_w1 + (size_t)l * DIM * MLP, W1T, DIM, MLP);
        tr_k<<<dim3(DIM / 32, MLP / 32), dim3(32, 8), 0, stream>>>(
            ff_w2 + (size_t)l * MLP * DIM, W2T, MLP, DIM);

        ln_k<<<MROWS, 64, 0, stream>>>(X, ln1_s + l * DIM, ln1_b + l * DIM, H);
        {
            dim3 g(QKVDIM / 128, (MROWS + 127) / 128);
            mgemm_k<0><<<g, 256, 0, stream>>>(H, WqT, nullptr, QKV, MROWS, QKVDIM, DIM);
        }
        attn_k<<<BT * HEADS, 256, 0, stream>>>(QKV, Ob);
        {
            dim3 g(DIM / 128, (MROWS + 127) / 128);
            mgemm_k<1><<<g, 256, 0, stream>>>(Ob, WoT, out_b + l * DIM, X, MROWS, DIM, INNER);
        }
        ln_k<<<MROWS, 64, 0, stream>>>(X, ln2_s + l * DIM, ln2_b + l * DIM, H);
        {
            dim3 g(MLP / 128, (MROWS + 127) / 128);
            mgemm_k<2><<<g, 256, 0, stream>>>(H, W1T, ff_b1 + l * MLP, F, MROWS, MLP, DIM);
        }
        {
            dim3 g(DIM / 128, (MROWS + 127) / 128);
            mgemm_k<1><<<g, 256, 0, stream>>>(F, W2T, ff_w2b + l * DIM, X, MROWS, DIM, MLP);
        }
    }

    // 3) outputs
    out_k<<<(BT * NTOK * DIM) / 256, 256, 0, stream>>>(X, outp);
}